// Round 1
// baseline (111.616 us; speedup 1.0000x reference)
//
#include <hip/hip_runtime.h>

// AdversarialFeatureDropout: B=2048, S=128, F=256, N_DROP=200
// out[b,s,f] = (mimic_b && f==fm_b) ? mv_b
//            : x[b,s,f] * ((f==p0_b && drop_any_b)||(f==p1_b && drop_two_b) ? 0 : 1)

#define AFD_B 2048
#define AFD_S 128
#define AFD_F 256

// float4s per sample = S*F/4 = 128*64 = 8192
#define F4_PER_SAMPLE 8192

__global__ __launch_bounds__(256) void afd_kernel(
    const float* __restrict__ x,
    const float* __restrict__ benign_means,
    const float* __restrict__ r,
    const int*   __restrict__ y,
    const int*   __restrict__ perm2,
    const int*   __restrict__ feat_mimic,
    float* __restrict__ out)
{
    const int b = blockIdx.x;

    // per-sample scalars (uniform across block -> scalar loads / L1 broadcast)
    const float rb = r[b];
    const bool drop_any = rb < 0.45f;
    const bool drop_two = rb < 0.15f;
    const int  yb = y[b];
    const bool mimic = (rb >= 0.45f) && (rb < 0.55f) && (yb < 10);
    const int  fm = feat_mimic[b];
    const int  p0 = perm2[2 * b];
    const int  p1 = perm2[2 * b + 1];
    const float mv = mimic ? benign_means[yb * AFD_F + fm] : 0.0f;

    // each thread owns feature-quad (tid & 63) -> predicates are loop-invariant
    const int f0 = (threadIdx.x & 63) << 2;

    float mmul[4];
    bool  usem[4];
    #pragma unroll
    for (int j = 0; j < 4; ++j) {
        const int f = f0 + j;
        const bool dropped = ((f == p0) && drop_any) || ((f == p1) && drop_two);
        mmul[j] = dropped ? 0.0f : 1.0f;
        usem[j] = mimic && (f == fm);
    }

    const float4* __restrict__ xb = reinterpret_cast<const float4*>(x) + (size_t)b * F4_PER_SAMPLE;
    float4* __restrict__ ob = reinterpret_cast<float4*>(out) + (size_t)b * F4_PER_SAMPLE;

    for (int inner = threadIdx.x; inner < F4_PER_SAMPLE; inner += 256) {
        float4 v = xb[inner];
        float4 o;
        o.x = usem[0] ? mv : v.x * mmul[0];
        o.y = usem[1] ? mv : v.y * mmul[1];
        o.z = usem[2] ? mv : v.z * mmul[2];
        o.w = usem[3] ? mv : v.w * mmul[3];
        ob[inner] = o;
    }
}

extern "C" void kernel_launch(void* const* d_in, const int* in_sizes, int n_in,
                              void* d_out, int out_size, void* d_ws, size_t ws_size,
                              hipStream_t stream) {
    const float* x            = (const float*)d_in[0];
    const float* benign_means = (const float*)d_in[1];
    const float* r            = (const float*)d_in[2];
    const int*   y            = (const int*)d_in[3];
    const int*   perm2        = (const int*)d_in[4];
    const int*   feat_mimic   = (const int*)d_in[5];
    float* out = (float*)d_out;

    afd_kernel<<<AFD_B, 256, 0, stream>>>(x, benign_means, r, y, perm2, feat_mimic, out);
}

// Round 3
// 101.049 us; speedup vs baseline: 1.1046x; 1.1046x over previous
//
#include <hip/hip_runtime.h>

// AdversarialFeatureDropout: B=2048, S=128, F=256, N_DROP=200
// out[b,s,f] = (mimic_b && f==fm_b) ? mv_b
//            : x[b,s,f] * ((f==p0_b && drop_any_b)||(f==p1_b && drop_two_b) ? 0 : 1)

#define AFD_B 2048
#define AFD_S 128
#define AFD_F 256

// float4s per sample = S*F/4 = 128*64 = 8192
#define F4_PER_SAMPLE 8192

typedef float vfloat4 __attribute__((ext_vector_type(4)));

__global__ __launch_bounds__(256) void afd_kernel(
    const float* __restrict__ x,
    const float* __restrict__ benign_means,
    const float* __restrict__ r,
    const int*   __restrict__ y,
    const int*   __restrict__ perm2,
    const int*   __restrict__ feat_mimic,
    float* __restrict__ out)
{
    const int b = blockIdx.x;

    // per-sample scalars (uniform across block)
    const float rb = r[b];
    const bool drop_any = rb < 0.45f;
    const bool drop_two = rb < 0.15f;
    const int  yb = y[b];
    const bool mimic = (rb >= 0.45f) && (rb < 0.55f) && (yb < 10);
    const int  fm = feat_mimic[b];
    const int  p0 = perm2[2 * b];
    const int  p1 = perm2[2 * b + 1];
    const float mv = mimic ? benign_means[yb * AFD_F + fm] : 0.0f;

    // each thread owns feature-quad (tid & 63) -> predicates loop-invariant
    const int f0 = (threadIdx.x & 63) << 2;

    float mmul[4];
    bool  usem[4];
    #pragma unroll
    for (int j = 0; j < 4; ++j) {
        const int f = f0 + j;
        const bool dropped = ((f == p0) && drop_any) || ((f == p1) && drop_two);
        mmul[j] = dropped ? 0.0f : 1.0f;
        usem[j] = mimic && (f == fm);
    }

    const vfloat4* __restrict__ xb = reinterpret_cast<const vfloat4*>(x) + (size_t)b * F4_PER_SAMPLE;
    vfloat4* __restrict__ ob = reinterpret_cast<vfloat4*>(out) + (size_t)b * F4_PER_SAMPLE;

    // 8192 / 256 = 32 iterations; unroll 4 -> 4 independent nt-loads in flight
    for (int base = 0; base < F4_PER_SAMPLE; base += 4 * 256) {
        const int i0 = base + threadIdx.x;
        vfloat4 v[4];
        #pragma unroll
        for (int u = 0; u < 4; ++u)
            v[u] = __builtin_nontemporal_load(&xb[i0 + u * 256]);
        #pragma unroll
        for (int u = 0; u < 4; ++u) {
            vfloat4 o;
            o.x = usem[0] ? mv : v[u].x * mmul[0];
            o.y = usem[1] ? mv : v[u].y * mmul[1];
            o.z = usem[2] ? mv : v[u].z * mmul[2];
            o.w = usem[3] ? mv : v[u].w * mmul[3];
            __builtin_nontemporal_store(o, &ob[i0 + u * 256]);
        }
    }
}

extern "C" void kernel_launch(void* const* d_in, const int* in_sizes, int n_in,
                              void* d_out, int out_size, void* d_ws, size_t ws_size,
                              hipStream_t stream) {
    const float* x            = (const float*)d_in[0];
    const float* benign_means = (const float*)d_in[1];
    const float* r            = (const float*)d_in[2];
    const int*   y            = (const int*)d_in[3];
    const int*   perm2        = (const int*)d_in[4];
    const int*   feat_mimic   = (const int*)d_in[5];
    float* out = (float*)d_out;

    afd_kernel<<<AFD_B, 256, 0, stream>>>(x, benign_means, r, y, perm2, feat_mimic, out);
}

// Round 4
// 99.723 us; speedup vs baseline: 1.1193x; 1.0133x over previous
//
#include <hip/hip_runtime.h>

// AdversarialFeatureDropout: B=2048, S=128, F=256, N_DROP=200
// out[b,s,f] = (mimic_b && f==fm_b) ? mv_b
//            : x[b,s,f] * ((f==p0_b && drop_any_b)||(f==p1_b && drop_two_b) ? 0 : 1)

#define AFD_B 2048
#define AFD_S 128
#define AFD_F 256

// float4s per sample = S*F/4 = 128*64 = 8192
#define F4_PER_SAMPLE 8192

typedef float vfloat4 __attribute__((ext_vector_type(4)));

__global__ __launch_bounds__(256) void afd_kernel(
    const float* __restrict__ x,
    const float* __restrict__ benign_means,
    const float* __restrict__ r,
    const int*   __restrict__ y,
    const int*   __restrict__ perm2,
    const int*   __restrict__ feat_mimic,
    float* __restrict__ out)
{
    const int b = blockIdx.x;

    // per-sample scalars (uniform across block)
    const float rb = r[b];
    const bool drop_any = rb < 0.45f;
    const bool drop_two = rb < 0.15f;
    const int  yb = y[b];
    const bool mimic = (rb >= 0.45f) && (rb < 0.55f) && (yb < 10);
    const int  fm = feat_mimic[b];
    const int  p0 = perm2[2 * b];
    const int  p1 = perm2[2 * b + 1];
    const float mv = mimic ? benign_means[yb * AFD_F + fm] : 0.0f;

    // each thread owns feature-quad (tid & 63) -> predicates loop-invariant
    const int f0 = (threadIdx.x & 63) << 2;

    float mmul[4];
    bool  usem[4];
    #pragma unroll
    for (int j = 0; j < 4; ++j) {
        const int f = f0 + j;
        const bool dropped = ((f == p0) && drop_any) || ((f == p1) && drop_two);
        mmul[j] = dropped ? 0.0f : 1.0f;
        usem[j] = mimic && (f == fm);
    }

    const vfloat4* __restrict__ xb = reinterpret_cast<const vfloat4*>(x) + (size_t)b * F4_PER_SAMPLE;
    vfloat4* __restrict__ ob = reinterpret_cast<vfloat4*>(out) + (size_t)b * F4_PER_SAMPLE;

    // 8192 / 256 = 32 per thread; unroll 8 -> 8 independent nt-loads in flight,
    // then an 8-deep store burst (longer same-direction DRAM runs).
    for (int base = 0; base < F4_PER_SAMPLE; base += 8 * 256) {
        const int i0 = base + threadIdx.x;
        vfloat4 v[8];
        #pragma unroll
        for (int u = 0; u < 8; ++u)
            v[u] = __builtin_nontemporal_load(&xb[i0 + u * 256]);
        #pragma unroll
        for (int u = 0; u < 8; ++u) {
            vfloat4 o;
            o.x = usem[0] ? mv : v[u].x * mmul[0];
            o.y = usem[1] ? mv : v[u].y * mmul[1];
            o.z = usem[2] ? mv : v[u].z * mmul[2];
            o.w = usem[3] ? mv : v[u].w * mmul[3];
            __builtin_nontemporal_store(o, &ob[i0 + u * 256]);
        }
    }
}

extern "C" void kernel_launch(void* const* d_in, const int* in_sizes, int n_in,
                              void* d_out, int out_size, void* d_ws, size_t ws_size,
                              hipStream_t stream) {
    const float* x            = (const float*)d_in[0];
    const float* benign_means = (const float*)d_in[1];
    const float* r            = (const float*)d_in[2];
    const int*   y            = (const int*)d_in[3];
    const int*   perm2        = (const int*)d_in[4];
    const int*   feat_mimic   = (const int*)d_in[5];
    float* out = (float*)d_out;

    afd_kernel<<<AFD_B, 256, 0, stream>>>(x, benign_means, r, y, perm2, feat_mimic, out);
}

// Round 5
// 84.313 us; speedup vs baseline: 1.3238x; 1.1828x over previous
//
#include <hip/hip_runtime.h>

// AdversarialFeatureDropout: B=2048, S=128, F=256, N_DROP=200
// out[b,s,f] = (mimic_b && f==fm_b) ? mv_b
//            : x[b,s,f] * ((f==p0_b && drop_any_b)||(f==p1_b && drop_two_b) ? 0 : 1)

#define AFD_B 2048
#define AFD_S 128
#define AFD_F 256

// float4s per sample = S*F/4 = 128*64 = 8192
#define F4_PER_SAMPLE 8192

typedef float vfloat4 __attribute__((ext_vector_type(4)));

__global__ __launch_bounds__(256) void afd_kernel(
    const float* __restrict__ x,
    const float* __restrict__ benign_means,
    const float* __restrict__ r,
    const int*   __restrict__ y,
    const int*   __restrict__ perm2,
    const int*   __restrict__ feat_mimic,
    float* __restrict__ out)
{
    const int b = blockIdx.x;

    // per-sample scalars (uniform across block)
    const float rb = r[b];
    const bool drop_any = rb < 0.45f;
    const bool drop_two = rb < 0.15f;
    const int  yb = y[b];
    const bool mimic = (rb >= 0.45f) && (rb < 0.55f) && (yb < 10);
    const int  fm = feat_mimic[b];
    const int  p0 = perm2[2 * b];
    const int  p1 = perm2[2 * b + 1];
    const float mv = mimic ? benign_means[yb * AFD_F + fm] : 0.0f;

    // each thread owns feature-quad (tid & 63) -> predicates loop-invariant
    const int f0 = (threadIdx.x & 63) << 2;

    float mmul[4];
    bool  usem[4];
    #pragma unroll
    for (int j = 0; j < 4; ++j) {
        const int f = f0 + j;
        const bool dropped = ((f == p0) && drop_any) || ((f == p1) && drop_two);
        mmul[j] = dropped ? 0.0f : 1.0f;
        usem[j] = mimic && (f == fm);
    }

    const vfloat4* __restrict__ xb = reinterpret_cast<const vfloat4*>(x) + (size_t)b * F4_PER_SAMPLE;
    vfloat4* __restrict__ ob = reinterpret_cast<vfloat4*>(out) + (size_t)b * F4_PER_SAMPLE;

    // nt-LOAD only (touch-once read stream, skip cache allocation);
    // REGULAR stores (let L2 write-combine like fillBuffer's 7 TB/s path).
    for (int base = 0; base < F4_PER_SAMPLE; base += 8 * 256) {
        const int i0 = base + threadIdx.x;
        vfloat4 v[8];
        #pragma unroll
        for (int u = 0; u < 8; ++u)
            v[u] = __builtin_nontemporal_load(&xb[i0 + u * 256]);
        #pragma unroll
        for (int u = 0; u < 8; ++u) {
            vfloat4 o;
            o.x = usem[0] ? mv : v[u].x * mmul[0];
            o.y = usem[1] ? mv : v[u].y * mmul[1];
            o.z = usem[2] ? mv : v[u].z * mmul[2];
            o.w = usem[3] ? mv : v[u].w * mmul[3];
            ob[i0 + u * 256] = o;
        }
    }
}

extern "C" void kernel_launch(void* const* d_in, const int* in_sizes, int n_in,
                              void* d_out, int out_size, void* d_ws, size_t ws_size,
                              hipStream_t stream) {
    const float* x            = (const float*)d_in[0];
    const float* benign_means = (const float*)d_in[1];
    const float* r            = (const float*)d_in[2];
    const int*   y            = (const int*)d_in[3];
    const int*   perm2        = (const int*)d_in[4];
    const int*   feat_mimic   = (const int*)d_in[5];
    float* out = (float*)d_out;

    afd_kernel<<<AFD_B, 256, 0, stream>>>(x, benign_means, r, y, perm2, feat_mimic, out);
}